// Round 17
// baseline (474.239 us; speedup 1.0000x reference)
//
#include <hip/hip_runtime.h>
#include <math.h>

#define BB 32
#define PP 128
#define NN 1000
#define EMB 128
#define HH 8
#define FFH 128
#define PEN -100000.0f
#define CLIP 10.0f
#define EPS 1e-5f

// ================== MEGA 1: kv-gemm | topk | q-gemm | transpose_mask ==================
// grid = 3136 x 512 thr.
// [0,512) kv-gemm, [512,1024) topk, [1024,1088) q-gemm, [1088,3136) transpose
__global__ __launch_bounds__(512) void mega1(
    const float* __restrict__ enc, const float* __restrict__ Wk, const float* __restrict__ Wv,
    float* __restrict__ Kb, float* __restrict__ Vb,
    const float* __restrict__ eln, const float* __restrict__ load,
    const float* __restrict__ Wq, float* __restrict__ Q,
    const float* __restrict__ mask, float* __restrict__ maskT,
    const float* __restrict__ dist, const float* __restrict__ theta,
    const float* __restrict__ f0, const float* __restrict__ f1,
    float* __restrict__ XS0, float* __restrict__ XS1,
    float* __restrict__ SD0, float* __restrict__ SD1, int* __restrict__ IDX) {
    __shared__ float smem[8448];
    int blk = blockIdx.x;
    int tid = threadIdx.x;
    if (blk < 512) {
        // ---- K/V projection: 125 nodes x 128 cols, K=128 in 32-k chunks ----
        int half = blk & 1, chunk = (blk >> 1) & 7, b = blk >> 4;
        const float* W = half ? Wv : Wk;
        float* Ob = half ? Vb : Kb;
        int n0 = chunk * 125;
        float* A_s = smem;          // [32][132]
        float* B_s = smem + 4224;   // [32][132]
        int tr = tid >> 5, tc = tid & 31;
        float acc[8][4];
#pragma unroll
        for (int i = 0; i < 8; i++)
#pragma unroll
            for (int j = 0; j < 4; j++) acc[i][j] = 0.f;
        for (int kk = 0; kk < 128; kk += 32) {
            if (kk) __syncthreads();
            for (int f = tid; f < 1000; f += 512) {
                int node = f >> 3, k4 = (f & 7) * 4;
                float4 v = *(const float4*)(enc + ((size_t)(b * 1000) + n0 + node) * 128
                                            + kk + k4);
                A_s[(k4 + 0) * 132 + node] = v.x;
                A_s[(k4 + 1) * 132 + node] = v.y;
                A_s[(k4 + 2) * 132 + node] = v.z;
                A_s[(k4 + 3) * 132 + node] = v.w;
            }
            for (int f = tid; f < 1024; f += 512) {
                int k = f >> 5, c4 = (f & 31) * 4;
                *(float4*)&B_s[k * 132 + c4] = *(const float4*)(W + (size_t)(kk + k) * 128 + c4);
            }
            __syncthreads();
#pragma unroll 8
            for (int k = 0; k < 32; ++k) {
                float av[8], bv[4];
                *(float4*)&av[0] = *(const float4*)&A_s[k * 132 + tr * 8];
                *(float4*)&av[4] = *(const float4*)&A_s[k * 132 + tr * 8 + 4];
                *(float4*)&bv[0] = *(const float4*)&B_s[k * 132 + tc * 4];
#pragma unroll
                for (int i = 0; i < 8; ++i)
#pragma unroll
                    for (int j = 0; j < 4; ++j) acc[i][j] = fmaf(av[i], bv[j], acc[i][j]);
            }
        }
#pragma unroll
        for (int i = 0; i < 8; ++i) {
            int node = tr * 8 + i;
            if (node < 125) {
                float4 o = {acc[i][0], acc[i][1], acc[i][2], acc[i][3]};
                *(float4*)(Ob + ((size_t)(b * 1000) + n0 + node) * 128 + tc * 4) = o;
            }
        }
    } else if (blk < 1024) {
        // ---- top-21 + xs rows: 8 bp per block, one wave each, register-only ----
        int w = tid >> 6, lane = tid & 63;
        int bp = (blk - 512) * 8 + w;
        const float* drow = dist + (size_t)bp * 1000;
        unsigned long long key[16];
#pragma unroll
        for (int j = 0; j < 16; ++j) {
            int n = j * 64 + lane;
            key[j] = (n < 1000)
                ? ((((unsigned long long)__float_as_uint(drow[n])) << 32) | (unsigned)n)
                : ~0ull;
        }
        float myv = 0.f, v10 = 0.f, v20 = 0.f;
        int myi = 0;
        for (int t = 0; t < 21; ++t) {
            unsigned long long kmin = key[0];
            int jm = 0;
#pragma unroll
            for (int j = 1; j < 16; ++j)
                if (key[j] < kmin) { kmin = key[j]; jm = j; }
            unsigned long long g = kmin;
#pragma unroll
            for (int o = 1; o < 64; o <<= 1) {
                unsigned long long o2 = __shfl_xor(g, o, 64);
                g = (o2 < g) ? o2 : g;
            }
            if (kmin == g) key[jm] = ~0ull;
            float gv = __uint_as_float((unsigned)(g >> 32));
            if (t == lane) { myv = gv; myi = (int)(g & 0xffffffffu); }
            if (t == 10) v10 = gv;
            if (t == 20) v20 = gv;
        }
        if (lane < 21) {
            float th = theta[(size_t)bp * 1000 + myi];
            IDX[(size_t)bp * 21 + lane] = myi;
            float sd1 = myv / v20;
            XS1[(size_t)bp * 44 + lane] = sd1;
            XS1[(size_t)bp * 44 + 21 + lane] = th;
            SD1[(size_t)bp * 21 + lane] = sd1;
            if (lane < 11) {
                float sd0 = myv / v10;
                XS0[(size_t)bp * 24 + lane] = sd0;
                XS0[(size_t)bp * 24 + 11 + lane] = th;
                SD0[(size_t)bp * 11 + lane] = sd0;
            }
        }
        if (lane == 0) {
            float a = f0[bp], c = f1[bp];
            XS0[(size_t)bp * 24 + 22] = a;
            XS0[(size_t)bp * 24 + 23] = c;
            XS1[(size_t)bp * 44 + 42] = a;
            XS1[(size_t)bp * 44 + 43] = c;
        }
    } else if (blk < 1088) {
        // ---- Q projection as GEMM: 64 rows x 128 cols, K=128 in 32-k chunks + load col ----
        int r0 = (blk - 1024) * 64;
        float* A_s = smem;          // [32][68]
        float* B_s = smem + 2176;   // [32][132]
        int tr = tid >> 5, tc = tid & 31;
        float acc[4][4];
#pragma unroll
        for (int i = 0; i < 4; i++)
#pragma unroll
            for (int j = 0; j < 4; j++) acc[i][j] = 0.f;
        for (int kk = 0; kk < 128; kk += 32) {
            if (kk) __syncthreads();
            for (int f = tid; f < 512; f += 512) {
                int row = f >> 3, k4 = (f & 7) * 4;
                float4 v = *(const float4*)(eln + (size_t)(r0 + row) * 128 + kk + k4);
                A_s[(k4 + 0) * 68 + row] = v.x;
                A_s[(k4 + 1) * 68 + row] = v.y;
                A_s[(k4 + 2) * 68 + row] = v.z;
                A_s[(k4 + 3) * 68 + row] = v.w;
            }
            for (int f = tid; f < 1024; f += 512) {
                int k = f >> 5, c4 = (f & 31) * 4;
                *(float4*)&B_s[k * 132 + c4] = *(const float4*)(Wq + (size_t)(kk + k) * 128 + c4);
            }
            __syncthreads();
#pragma unroll 8
            for (int k = 0; k < 32; ++k) {
                float av[4], bv[4];
                *(float4*)&av[0] = *(const float4*)&A_s[k * 68 + tr * 4];
                *(float4*)&bv[0] = *(const float4*)&B_s[k * 132 + tc * 4];
#pragma unroll
                for (int i = 0; i < 4; ++i)
#pragma unroll
                    for (int j = 0; j < 4; ++j) acc[i][j] = fmaf(av[i], bv[j], acc[i][j]);
            }
        }
#pragma unroll
        for (int i = 0; i < 4; ++i) {
            int row = r0 + tr * 4 + i;
            float lv = load[row];
#pragma unroll
            for (int j = 0; j < 4; ++j) {
                float wv = Wq[16384 + tc * 4 + j];
                acc[i][j] = fmaf(lv, wv, acc[i][j]) * 0.25f;
            }
            float4 o = {acc[i][0], acc[i][1], acc[i][2], acc[i][3]};
            *(float4*)(Q + (size_t)row * 128 + tc * 4) = o;
        }
    } else {
        // ---- mask transpose: two 32x32 tiles per block ----
        int t2 = (blk - 1088) * 2 + (tid >> 8);
        int tl = tid & 255;
        int b = t2 >> 7, pt = (t2 >> 5) & 3, nt = t2 & 31;
        int tx = tl & 31, ty = tl >> 5;
        float* t = smem + (tid >> 8) * 1056;  // [32][33]
        int p0 = pt * 32, n0 = nt * 32;
#pragma unroll
        for (int r = 0; r < 32; r += 8) {
            int pp = p0 + ty + r, nn = n0 + tx;
            t[(ty + r) * 33 + tx] = (nn < 1000) ? mask[((size_t)b * 128 + pp) * 1000 + nn] : 0.f;
        }
        __syncthreads();
#pragma unroll
        for (int r = 0; r < 32; r += 8) {
            int nn = n0 + ty + r, pp = p0 + tx;
            if (nn < 1000) maskT[((size_t)b * 1000 + nn) * 128 + pp] = t[tx * 33 + ty + r];
        }
    }
}

// ================== ATTENTION: 16 waves/block, full-n, K+V in LDS, 1-deep prefetch ==================
// grid = 256 (b = blk&31, h = blk>>5), 1024 thr. thread = (pg 0..31 [4 p's], ng 0..31 [n strided 32]).
__global__ __launch_bounds__(1024) void attn6(const float* __restrict__ Q,
                                              const float* __restrict__ Kb,
                                              const float* __restrict__ Vb,
                                              const float* __restrict__ maskT,
                                              float* __restrict__ OC) {
    int blk = blockIdx.x;
    int b = blk & 31, h = blk >> 5;
    int tid = threadIdx.x;
    __shared__ float lds[32000];  // K[1000][16] | V[1000][16]; later part[8][128][20]
    float4* K4 = (float4*)lds;
    float4* V4 = (float4*)(lds + 16000);
    const size_t baseKV = (size_t)b * 128000 + h * 16;
    for (int f = tid; f < 4000; f += 1024) {
        int n = f >> 2, d4 = f & 3;
        K4[f] = *(const float4*)(Kb + baseKV + (size_t)n * 128 + d4 * 4);
        V4[f] = *(const float4*)(Vb + baseKV + (size_t)n * 128 + d4 * 4);
    }
    int pg = tid & 31, ng = tid >> 5;  // ng 0..31
    int p0 = pg * 4;
    float4 qr[4][4];
#pragma unroll
    for (int j = 0; j < 4; ++j) {
        const float* qp = Q + ((size_t)(b * 128 + p0 + j)) * 128 + h * 16;
#pragma unroll
        for (int d4 = 0; d4 < 4; ++d4) qr[j][d4] = *(const float4*)(qp + d4 * 4);
    }
    const float* mT = maskT + (size_t)b * 128000 + p0;
    __syncthreads();

    float4 z = {0.f, 0.f, 0.f, 0.f};
    float4 Oa[4][4];
    float l4[4] = {0.f, 0.f, 0.f, 0.f};
#pragma unroll
    for (int j = 0; j < 4; ++j)
#pragma unroll
        for (int d4 = 0; d4 < 4; ++d4) Oa[j][d4] = z;

    // 1000 = 8*32 + ... : ng<8 -> 32 iters, else 31. Wave holds ng {2w,2w+1} -> uniform.
    int nlim = (ng < 8) ? 32 : 31;
    int n = ng;
    float4 k0 = K4[n * 4], k1 = K4[n * 4 + 1], k2 = K4[n * 4 + 2], k3 = K4[n * 4 + 3];
    float4 v0 = V4[n * 4], v1 = V4[n * 4 + 1], v2 = V4[n * 4 + 2], v3 = V4[n * 4 + 3];
    float4 mv = *(const float4*)(mT + (size_t)n * 128);
#pragma unroll 1
    for (int i = 0; i < nlim; ++i) {
        int nn = n + 32;
        nn = (nn < 1000) ? nn : n;  // clamp (dead on last iter)
        int nn4 = nn * 4;
        float4 K0 = K4[nn4], K1 = K4[nn4 + 1], K2 = K4[nn4 + 2], K3 = K4[nn4 + 3];
        float4 V0 = V4[nn4], V1 = V4[nn4 + 1], V2 = V4[nn4 + 2], V3 = V4[nn4 + 3];
        float4 MV = *(const float4*)(mT + (size_t)nn * 128);
        float mva[4] = {mv.x, mv.y, mv.z, mv.w};
#pragma unroll
        for (int j = 0; j < 4; ++j) {
            float sA = qr[j][0].x * k0.x;
            sA = fmaf(qr[j][0].y, k0.y, sA);
            sA = fmaf(qr[j][0].z, k0.z, sA);
            sA = fmaf(qr[j][0].w, k0.w, sA);
            sA = fmaf(qr[j][1].x, k1.x, sA);
            sA = fmaf(qr[j][1].y, k1.y, sA);
            sA = fmaf(qr[j][1].z, k1.z, sA);
            sA = fmaf(qr[j][1].w, k1.w, sA);
            float sB = fmaf(qr[j][2].x, k2.x, mva[j]);
            sB = fmaf(qr[j][2].y, k2.y, sB);
            sB = fmaf(qr[j][2].z, k2.z, sB);
            sB = fmaf(qr[j][2].w, k2.w, sB);
            sB = fmaf(qr[j][3].x, k3.x, sB);
            sB = fmaf(qr[j][3].y, k3.y, sB);
            sB = fmaf(qr[j][3].z, k3.z, sB);
            sB = fmaf(qr[j][3].w, k3.w, sB);
            float e = __expf(sA + sB);
            l4[j] += e;
            Oa[j][0].x = fmaf(e, v0.x, Oa[j][0].x);
            Oa[j][0].y = fmaf(e, v0.y, Oa[j][0].y);
            Oa[j][0].z = fmaf(e, v0.z, Oa[j][0].z);
            Oa[j][0].w = fmaf(e, v0.w, Oa[j][0].w);
            Oa[j][1].x = fmaf(e, v1.x, Oa[j][1].x);
            Oa[j][1].y = fmaf(e, v1.y, Oa[j][1].y);
            Oa[j][1].z = fmaf(e, v1.z, Oa[j][1].z);
            Oa[j][1].w = fmaf(e, v1.w, Oa[j][1].w);
            Oa[j][2].x = fmaf(e, v2.x, Oa[j][2].x);
            Oa[j][2].y = fmaf(e, v2.y, Oa[j][2].y);
            Oa[j][2].z = fmaf(e, v2.z, Oa[j][2].z);
            Oa[j][2].w = fmaf(e, v2.w, Oa[j][2].w);
            Oa[j][3].x = fmaf(e, v3.x, Oa[j][3].x);
            Oa[j][3].y = fmaf(e, v3.y, Oa[j][3].y);
            Oa[j][3].z = fmaf(e, v3.z, Oa[j][3].z);
            Oa[j][3].w = fmaf(e, v3.w, Oa[j][3].w);
        }
        k0 = K0; k1 = K1; k2 = K2; k3 = K3;
        v0 = V0; v1 = V1; v2 = V2; v3 = V3;
        mv = MV;
        n = nn;
    }
    // merge lane^32 (wave's two ng) in-register
#pragma unroll
    for (int j = 0; j < 4; ++j) {
        l4[j] += __shfl_xor(l4[j], 32, 64);
#pragma unroll
        for (int d4 = 0; d4 < 4; ++d4) {
            Oa[j][d4].x += __shfl_xor(Oa[j][d4].x, 32, 64);
            Oa[j][d4].y += __shfl_xor(Oa[j][d4].y, 32, 64);
            Oa[j][d4].z += __shfl_xor(Oa[j][d4].z, 32, 64);
            Oa[j][d4].w += __shfl_xor(Oa[j][d4].w, 32, 64);
        }
    }
    __syncthreads();  // all K/V reads done before aliasing
    float* part = lds;  // [8 buf][128 p][20]
    int w = tid >> 6;   // wave 0..15
    bool lead = (tid & 32) == 0;
    if (w >= 8 && lead) {  // round 1: waves 8..15 write buffers 0..7
        float* pb = part + (w - 8) * 2560;
#pragma unroll
        for (int j = 0; j < 4; ++j) {
            float* pr = pb + (p0 + j) * 20;
#pragma unroll
            for (int d4 = 0; d4 < 4; ++d4) *(float4*)(pr + d4 * 4) = Oa[j][d4];
            pr[16] = l4[j];
        }
    }
    __syncthreads();
    if (w < 8 && lead) {  // round 2: waves 0..7 accumulate
        float* pb = part + w * 2560;
#pragma unroll
        for (int j = 0; j < 4; ++j) {
            float* pr = pb + (p0 + j) * 20;
#pragma unroll
            for (int d4 = 0; d4 < 4; ++d4) {
                float4 t = *(const float4*)(pr + d4 * 4);
                t.x += Oa[j][d4].x; t.y += Oa[j][d4].y;
                t.z += Oa[j][d4].z; t.w += Oa[j][d4].w;
                *(float4*)(pr + d4 * 4) = t;
            }
            pr[16] += l4[j];
        }
    }
    __syncthreads();
    if (tid < 512) {
        int p = tid >> 2, dg = tid & 3;
        float lsum = 0.f;
        float4 o = z;
#pragma unroll
        for (int w2 = 0; w2 < 8; ++w2) {
            const float* pr = part + w2 * 2560 + p * 20;
            lsum += pr[16];
            float4 t = *(const float4*)(pr + dg * 4);
            o.x += t.x; o.y += t.y; o.z += t.z; o.w += t.w;
        }
        float inv = 1.f / lsum;
        float4 r = {o.x * inv, o.y * inv, o.z * inv, o.w * inv};
        *(float4*)(OC + ((size_t)(b * 128 + p)) * 128 + h * 16 + dg * 4) = r;
    }
}

// ================== POLICY FRONT: standalone ==================
__global__ __launch_bounds__(512) void pfront(
    const float* __restrict__ XS0, const float* __restrict__ XS1,
    const float* __restrict__ w1_0, const float* __restrict__ b1_0,
    const float* __restrict__ w2_0, const float* __restrict__ b2_0,
    const float* __restrict__ w1_1, const float* __restrict__ b1_1,
    const float* __restrict__ w2_1, const float* __restrict__ b2_1,
    float* __restrict__ Hb0, float* __restrict__ Hb1) {
    __shared__ float smem[12320];
    int fb = blockIdx.x;
    int tid = threadIdx.x;
    int pol = fb & 1, colT = (fb >> 1) & 1, rowT = fb >> 2;
    int r0 = rowT * 64, c0 = colT * 128;
    const float* XS = pol ? XS1 : XS0;
    const float* w1 = pol ? w1_1 : w1_0;
    const float* b1 = pol ? b1_1 : b1_0;
    const float* w2 = pol ? w2_1 : w2_0;
    const float* b2 = pol ? b2_1 : b2_0;
    float* Hb = pol ? Hb1 : Hb0;
    int XSW = pol ? 44 : 24;
    float* xs_s = smem;          // [64][44]
    float* e_s = smem + 2816;    // [64][132]
    float* B_s = smem + 11264;   // [8][132]
    for (int f = tid; f < 64 * XSW; f += 512) {
        int r = f / XSW, k = f % XSW;
        xs_s[r * 44 + k] = XS[(size_t)(r0 + r) * XSW + k];
    }
    __syncthreads();
#pragma unroll
    for (int i = 0; i < 16; ++i) {
        int f = tid + i * 512;
        int r = f >> 7, c = f & 127;
        float acc = b1[c];
        for (int k = 0; k < XSW; ++k) acc = fmaf(xs_s[r * 44 + k], w1[k * 128 + c], acc);
        e_s[r * 132 + c] = fmaxf(acc, 0.f);
    }
    __syncthreads();
    int tr = tid >> 5, tc = tid & 31;
    float acc[4][4];
#pragma unroll
    for (int jj = 0; jj < 4; ++jj) {
        float bb = b2[c0 + tc * 4 + jj];
#pragma unroll
        for (int j = 0; j < 4; ++j) acc[j][jj] = bb;
    }
    for (int kk = 0; kk < 128; kk += 8) {
#pragma unroll
        for (int f = tid; f < 1024; f += 512) {
            int k = f >> 7, c = f & 127;
            B_s[k * 132 + c] = w2[(size_t)(kk + k) * 256 + c0 + c];
        }
        __syncthreads();
#pragma unroll
        for (int k = 0; k < 8; ++k) {
            float av[4], bv[4];
#pragma unroll
            for (int j = 0; j < 4; ++j) av[j] = e_s[(tr * 4 + j) * 132 + kk + k];
            *(float4*)&bv[0] = *(const float4*)&B_s[k * 132 + tc * 4];
#pragma unroll
            for (int j = 0; j < 4; ++j)
#pragma unroll
                for (int jj = 0; jj < 4; ++jj) acc[j][jj] = fmaf(av[j], bv[jj], acc[j][jj]);
        }
        __syncthreads();
    }
#pragma unroll
    for (int j = 0; j < 4; ++j) {
        float4 o = {fmaxf(acc[j][0], 0.f), fmaxf(acc[j][1], 0.f),
                    fmaxf(acc[j][2], 0.f), fmaxf(acc[j][3], 0.f)};
        *(float4*)(Hb + (size_t)(r0 + tr * 4 + j) * 256 + c0 + tc * 4) = o;
    }
}

// ================== MEGA 3: comb_proj | inorm ==================
__global__ __launch_bounds__(512) void mega3(
    const float* __restrict__ OC, const float* __restrict__ Wc, const float* __restrict__ bc,
    float* __restrict__ MH,
    const float* __restrict__ Hb0, const float* __restrict__ Hb1,
    float* __restrict__ MUb, float* __restrict__ RSb) {
    __shared__ float smem[1056];
    int blk = blockIdx.x;
    int tid = threadIdx.x;
    if (blk < 512) {
        int r0 = blk * 8;
        float* x_s = smem;  // [8][129]
#pragma unroll
        for (int f = tid; f < 1024; f += 512) {
            int r = f >> 7, c = f & 127;
            x_s[r * 129 + c] = OC[(size_t)(r0 + r) * 128 + c];
        }
        __syncthreads();
        int rr = tid >> 7, c = tid & 127;
        float a0 = bc[c], a1 = a0;
#pragma unroll 4
        for (int k = 0; k < 128; ++k) {
            float wv = Wc[k * 128 + c];
            a0 = fmaf(x_s[rr * 129 + k], wv, a0);
            a1 = fmaf(x_s[(rr + 4) * 129 + k], wv, a1);
        }
        MH[(size_t)(r0 + rr) * 128 + c] = a0;
        MH[(size_t)(r0 + rr + 4) * 128 + c] = a1;
    } else {
        int ib = blk - 512;
        int pol = ib & 1, b = ib >> 1;
        const float* Hb = pol ? Hb1 : Hb0;
        int c = tid & 255, half = tid >> 8;
        float s = 0.f, s2 = 0.f;
        int pbase = half * 64;
        for (int p = pbase; p < pbase + 64; ++p) {
            float v = Hb[((size_t)(b * 128 + p)) * 256 + c];
            s += v;
            s2 += v * v;
        }
        float* s_s = smem;
        float* s2_s = smem + 512;
        s_s[half * 256 + c] = s;
        s2_s[half * 256 + c] = s2;
        __syncthreads();
        if (half == 0) {
            float S = s_s[c] + s_s[256 + c];
            float S2 = s2_s[c] + s2_s[256 + c];
            float mu = S * (1.f / 128.f);
            float var = S2 * (1.f / 128.f) - mu * mu;
            MUb[pol * 8192 + b * 256 + c] = mu;
            RSb[pol * 8192 + b * 256 + c] = rsqrtf(var + EPS);
        }
    }
}

// ================== MEGA 4: policy_back (32-row tiles) | gemm_score ==================
// grid = 768 x 512 thr. [0,256) back, [256,768) score
__global__ __launch_bounds__(512) void mega4(
    const float* __restrict__ MH, const float* __restrict__ enc, float* __restrict__ SC,
    const float* __restrict__ Hb0, const float* __restrict__ Hb1,
    const float* __restrict__ MUb, const float* __restrict__ RSb,
    const float* __restrict__ g0, const float* __restrict__ be0,
    const float* __restrict__ w3_0, const float* __restrict__ b3_0,
    const float* __restrict__ w4_0, const float* __restrict__ b4_0,
    const float* __restrict__ g1, const float* __restrict__ be1,
    const float* __restrict__ w3_1, const float* __restrict__ b3_1,
    const float* __restrict__ w4_1, const float* __restrict__ b4_1,
    const float* __restrict__ SD0, const float* __restrict__ SD1,
    float* __restrict__ OUT0, float* __restrict__ OUT1) {
    __shared__ float smem[10112];
    int blk = blockIdx.x;
    int tid = threadIdx.x;
    if (blk < 256) {
        // ---- policy back: 32 rows x 128 cols, K=256 in 32-k chunks ----
        int pol = blk & 1, rowT = blk >> 1;
        int r0 = rowT * 32, b = r0 >> 7;
        const float* Hb = pol ? Hb1 : Hb0;
        const float* MU = MUb + pol * 8192 + b * 256;
        const float* RS = RSb + pol * 8192 + b * 256;
        const float* gg = pol ? g1 : g0;
        const float* bbv = pol ? be1 : be0;
        const float* w3 = pol ? w3_1 : w3_0;
        const float* pb3 = pol ? b3_1 : b3_0;
        const float* w4 = pol ? w4_1 : w4_0;
        const float* pb4 = pol ? b4_1 : b4_0;
        const float* SD = pol ? SD1 : SD0;
        float* OUT = pol ? OUT1 : OUT0;
        int ls = pol ? 21 : 11;
        float* scale_s = smem;            // [256]
        float* shift_s = smem + 256;      // [256]
        float* A_s = smem + 512;          // [32][36]
        float* B_s = smem + 1664;         // [32][132]
        float* e2_s = smem + 5888;        // [32][132]
        if (tid < 256) {
            float sc = RS[tid] * gg[tid];
            scale_s[tid] = sc;
            shift_s[tid] = bbv[tid] - MU[tid] * sc;
        }
        __syncthreads();
        int tr = tid >> 5, tc = tid & 31;
        float acc[2][4];
#pragma unroll
        for (int jj = 0; jj < 4; ++jj) {
            float bv = pb3[tc * 4 + jj];
            acc[0][jj] = bv;
            acc[1][jj] = bv;
        }
        for (int kk = 0; kk < 256; kk += 32) {
            if (kk) __syncthreads();
#pragma unroll
            for (int f = tid; f < 1024; f += 512) {
                int r = f >> 5, k = f & 31;
                float v = Hb[(size_t)(r0 + r) * 256 + kk + k];
                A_s[k * 36 + r] = v * scale_s[kk + k] + shift_s[kk + k];
            }
#pragma unroll
            for (int f = tid; f < 1024; f += 512) {
                int k = f >> 5, c4 = (f & 31) * 4;
                *(float4*)&B_s[k * 132 + c4] =
                    *(const float4*)(w3 + (size_t)(kk + k) * 128 + c4);
            }
            __syncthreads();
#pragma unroll 8
            for (int k = 0; k < 32; ++k) {
                float a0 = A_s[k * 36 + tr * 2];
                float a1 = A_s[k * 36 + tr * 2 + 1];
                float bv[4];
                *(float4*)&bv[0] = *(const float4*)&B_s[k * 132 + tc * 4];
#pragma unroll
                for (int jj = 0; jj < 4; ++jj) {
                    acc[0][jj] = fmaf(a0, bv[jj], acc[0][jj]);
                    acc[1][jj] = fmaf(a1, bv[jj], acc[1][jj]);
                }
            }
        }
        __syncthreads();
#pragma unroll
        for (int j = 0; j < 2; ++j) {
            float4 o = {fmaxf(acc[j][0], 0.f), fmaxf(acc[j][1], 0.f),
                        fmaxf(acc[j][2], 0.f), fmaxf(acc[j][3], 0.f)};
            *(float4*)&e2_s[(tr * 2 + j) * 132 + tc * 4] = o;
        }
        __syncthreads();
        for (int o = tid; o < 32 * ls; o += 512) {
            int row = o / ls, c = o % ls;
            float a = pb4[c];
#pragma unroll 4
            for (int k = 0; k < 128; ++k) a = fmaf(e2_s[row * 132 + k], w4[k * ls + c], a);
            OUT[(size_t)(r0 + row) * ls + c] = a - SD[(size_t)(r0 + row) * ls + c];
        }
    } else {
        // ---- node scores: 64 p x 125 n tile, K=128 in 32-k chunks, 4x4/thread ----
        int sb = blk - 256;
        int ph = sb & 1, chunk = (sb >> 1) & 7, b = sb >> 4;
        int n0 = chunk * 125, p0 = ph * 64;
        float* A_s = smem;          // [32][68]
        float* B_s = smem + 2176;   // [32][132]
        int tr = tid >> 5, tc = tid & 31;
        float acc[4][4];
#pragma unroll
        for (int i = 0; i < 4; i++)
#pragma unroll
            for (int j = 0; j < 4; j++) acc[i][j] = 0.f;
        for (int kk = 0; kk < 128; kk += 32) {
            if (kk) __syncthreads();
            for (int f = tid; f < 512; f += 512) {
                int row = f >> 3, k4 = (f & 7) * 4;
                float4 v = *(const float4*)(MH + ((size_t)(b * 128) + p0 + row) * 128 + kk + k4);
                A_s[(k4 + 0) * 68 + row] = v.x;
                A_s[(k4 + 1) * 68 + row] = v.y;
                A_s[(k4 + 2) * 68 + row] = v.z;
                A_s[(k4 + 3) * 68 + row] = v.w;
            }
            for (int f = tid; f < 1000; f += 512) {
                int nn = f >> 3, k4 = (f & 7) * 4;
                float4 v = *(const float4*)(enc + ((size_t)(b * 1000) + n0 + nn) * 128 + kk + k4);
                B_s[(k4 + 0) * 132 + nn] = v.x;
                B_s[(k4 + 1) * 132 + nn] = v.y;
                B_s[(k4 + 2) * 132 + nn] = v.z;
                B_s[(k4 + 3) * 132 + nn] = v.w;
            }
            __syncthreads();
#pragma unroll 8
            for (int k = 0; k < 32; ++k) {
                float av[4], bv[4];
                *(float4*)&av[0] = *(const float4*)&A_s[k * 68 + tr * 4];
                *(float4*)&bv[0] = *(const float4*)&B_s[k * 132 + tc * 4];
#pragma unroll
                for (int i = 0; i < 4; ++i)
#pragma unroll
                    for (int j = 0; j < 4; ++j) acc[i][j] = fmaf(av[i], bv[j], acc[i][j]);
            }
        }
        const float invs = 0.08838834764831845f;
#pragma unroll
        for (int i = 0; i < 4; ++i) {
            int pp = p0 + tr * 4 + i;
#pragma unroll
            for (int j = 0; j < 4; ++j) {
                int n = tc * 4 + j;
                if (n < 125) SC[((size_t)(b * 128) + pp) * 1000 + n0 + n] = acc[i][j] * invs;
            }
        }
    }
}

// ---------------- final softmax ----------------
__device__ inline float blockReduceMaxF(float v, volatile float* red) {
#pragma unroll
    for (int o = 32; o > 0; o >>= 1) v = fmaxf(v, __shfl_xor(v, o, 64));
    if ((threadIdx.x & 63) == 0) red[threadIdx.x >> 6] = v;
    __syncthreads();
    float r = fmaxf(fmaxf(red[0], red[1]), fmaxf(red[2], red[3]));
    __syncthreads();
    return r;
}

__device__ inline float blockReduceSumF(float v, volatile float* red) {
#pragma unroll
    for (int o = 32; o > 0; o >>= 1) v += __shfl_xor(v, o, 64);
    if ((threadIdx.x & 63) == 0) red[threadIdx.x >> 6] = v;
    __syncthreads();
    float r = red[0] + red[1] + red[2] + red[3];
    __syncthreads();
    return r;
}

__global__ void final_softmax(const float* SC, const float* __restrict__ mask,
                              const int* __restrict__ IDX, const float* __restrict__ OUT0,
                              const float* __restrict__ OUT1, float* out) {
    int bp = blockIdx.x;
    int tid = threadIdx.x;
    __shared__ float a0[1000];
    __shared__ float a1[1000];
    __shared__ float red[4];
    for (int n = tid; n < 1000; n += 256) {
        a0[n] = PEN;
        a1[n] = PEN;
    }
    __syncthreads();
    if (tid < 11) a0[IDX[bp * 21 + tid]] = OUT0[bp * 11 + tid];
    if (tid < 21) a1[IDX[bp * 21 + tid]] = OUT1[bp * 21 + tid];
    __syncthreads();
    float logit[4];
    float lmax = -INFINITY;
    {
        int i = 0;
        for (int n = tid; n < 1000; n += 256, i++) {
            float sc = SC[(size_t)bp * 1000 + n] + 0.5f * (a0[n] + a1[n]);
            float zz = __expf(2.f * sc);
            float t = 1.f - 2.f / (zz + 1.f);
            float lg = CLIP * t + mask[(size_t)bp * 1000 + n];
            logit[i] = lg;
            lmax = fmaxf(lmax, lg);
        }
    }
    float m = blockReduceMaxF(lmax, red);
    float lsum = 0.f;
    {
        int i = 0;
        for (int n = tid; n < 1000; n += 256, i++) {
            float e = __expf(logit[i] - m);
            logit[i] = e;
            lsum += e;
        }
    }
    float s = blockReduceSumF(lsum, red);
    float inv = 1.f / s;
    {
        int i = 0;
        for (int n = tid; n < 1000; n += 256, i++) out[(size_t)bp * 1000 + n] = logit[i] * inv;
    }
}

// ---------------- launcher ----------------
extern "C" void kernel_launch(void* const* d_in, const int* in_sizes, int n_in,
                              void* d_out, int out_size, void* d_ws, size_t ws_size,
                              hipStream_t stream) {
    const float* eln   = (const float*)d_in[0];
    const float* load  = (const float*)d_in[1];
    const float* dist  = (const float*)d_in[2];
    const float* theta = (const float*)d_in[3];
    const float* f0    = (const float*)d_in[4];
    const float* f1    = (const float*)d_in[5];
    const float* mask  = (const float*)d_in[6];
    const float* enc   = (const float*)d_in[7];
    const float* Wq    = (const float*)d_in[8];
    const float* Wk    = (const float*)d_in[9];
    const float* Wv    = (const float*)d_in[10];
    const float* Wc    = (const float*)d_in[11];
    const float* bc    = (const float*)d_in[12];
    const float* p0w1 = (const float*)d_in[13];
    const float* p0b1 = (const float*)d_in[14];
    const float* p0w2 = (const float*)d_in[15];
    const float* p0b2 = (const float*)d_in[16];
    const float* p0w3 = (const float*)d_in[17];
    const float* p0b3 = (const float*)d_in[18];
    const float* p0w4 = (const float*)d_in[19];
    const float* p0b4 = (const float*)d_in[20];
    const float* p0g  = (const float*)d_in[21];
    const float* p0be = (const float*)d_in[22];
    const float* p1w1 = (const float*)d_in[23];
    const float* p1b1 = (const float*)d_in[24];
    const float* p1w2 = (const float*)d_in[25];
    const float* p1b2 = (const float*)d_in[26];
    const float* p1w3 = (const float*)d_in[27];
    const float* p1b3 = (const float*)d_in[28];
    const float* p1w4 = (const float*)d_in[29];
    const float* p1b4 = (const float*)d_in[30];
    const float* p1g  = (const float*)d_in[31];
    const float* p1be = (const float*)d_in[32];

    float* out = (float*)d_out;

    float* ws = (float*)d_ws;
    float* Kb   = ws;                     // 4,096,000
    float* Vb   = Kb + 4096000;           // 4,096,000
    float* Qb   = Vb + 4096000;           // 524,288
    float* OCb  = Qb + 524288;            // 524,288
    float* MHb  = OCb + 524288;           // 524,288
    float* Hb0  = MHb + 524288;           // 1,048,576
    float* Hb1  = Hb0 + 1048576;          // 1,048,576
    float* MUb  = Hb1 + 1048576;          // 16,384
    float* RSb  = MUb + 16384;            // 16,384
    float* SD0  = RSb + 16384;            // 45,056
    float* SD1  = SD0 + 45056;            // 86,016
    float* OUT0 = SD1 + 86016;            // 45,056
    float* OUT1 = OUT0 + 45056;           // 86,016
    int*   IDX  = (int*)(OUT1 + 86016);   // 86,016 ints
    float* XS0  = (float*)(IDX + 86016);  // 98,304
    float* XS1  = XS0 + 98304;            // 180,224

    float* maskT = out;
    float* SC = out;

    mega1<<<3136, 512, 0, stream>>>(enc, Wk, Wv, Kb, Vb,
                                    eln, load, Wq, Qb,
                                    mask, maskT,
                                    dist, theta, f0, f1, XS0, XS1, SD0, SD1, IDX);
    attn6<<<256, 1024, 0, stream>>>(Qb, Kb, Vb, maskT, OCb);
    pfront<<<256, 512, 0, stream>>>(XS0, XS1,
                                    p0w1, p0b1, p0w2, p0b2,
                                    p1w1, p1b1, p1w2, p1b2,
                                    Hb0, Hb1);
    mega3<<<576, 512, 0, stream>>>(OCb, Wc, bc, MHb, Hb0, Hb1, MUb, RSb);
    mega4<<<768, 512, 0, stream>>>(MHb, enc, SC,
                                   Hb0, Hb1, MUb, RSb,
                                   p0g, p0be, p0w3, p0b3, p0w4, p0b4,
                                   p1g, p1be, p1w3, p1b3, p1w4, p1b4,
                                   SD0, SD1, OUT0, OUT1);
    final_softmax<<<BB * PP, 256, 0, stream>>>(SC, mask, IDX, OUT0, OUT1, out);
}

// Round 18
// 210.561 us; speedup vs baseline: 2.2523x; 2.2523x over previous
//
#include <hip/hip_runtime.h>
#include <math.h>

#define BB 32
#define PP 128
#define NN 1000
#define EMB 128
#define HH 8
#define FFH 128
#define PEN -100000.0f
#define CLIP 10.0f
#define EPS 1e-5f

// ================== MEGA 1: kv-gemm | topk | q-gemm | transpose_mask ==================
// grid = 3136 x 512 thr.
// [0,512) kv-gemm, [512,1024) topk, [1024,1088) q-gemm, [1088,3136) transpose
__global__ __launch_bounds__(512) void mega1(
    const float* __restrict__ enc, const float* __restrict__ Wk, const float* __restrict__ Wv,
    float* __restrict__ Kb, float* __restrict__ Vb,
    const float* __restrict__ eln, const float* __restrict__ load,
    const float* __restrict__ Wq, float* __restrict__ Q,
    const float* __restrict__ mask, float* __restrict__ maskT,
    const float* __restrict__ dist, const float* __restrict__ theta,
    const float* __restrict__ f0, const float* __restrict__ f1,
    float* __restrict__ XS0, float* __restrict__ XS1,
    float* __restrict__ SD0, float* __restrict__ SD1, int* __restrict__ IDX) {
    __shared__ float smem[8448];
    int blk = blockIdx.x;
    int tid = threadIdx.x;
    if (blk < 512) {
        // ---- K/V projection: 125 nodes x 128 cols, K=128 in 32-k chunks ----
        int half = blk & 1, chunk = (blk >> 1) & 7, b = blk >> 4;
        const float* W = half ? Wv : Wk;
        float* Ob = half ? Vb : Kb;
        int n0 = chunk * 125;
        float* A_s = smem;          // [32][132]
        float* B_s = smem + 4224;   // [32][132]
        int tr = tid >> 5, tc = tid & 31;
        float acc[8][4];
#pragma unroll
        for (int i = 0; i < 8; i++)
#pragma unroll
            for (int j = 0; j < 4; j++) acc[i][j] = 0.f;
        for (int kk = 0; kk < 128; kk += 32) {
            if (kk) __syncthreads();
            for (int f = tid; f < 1000; f += 512) {
                int node = f >> 3, k4 = (f & 7) * 4;
                float4 v = *(const float4*)(enc + ((size_t)(b * 1000) + n0 + node) * 128
                                            + kk + k4);
                A_s[(k4 + 0) * 132 + node] = v.x;
                A_s[(k4 + 1) * 132 + node] = v.y;
                A_s[(k4 + 2) * 132 + node] = v.z;
                A_s[(k4 + 3) * 132 + node] = v.w;
            }
            for (int f = tid; f < 1024; f += 512) {
                int k = f >> 5, c4 = (f & 31) * 4;
                *(float4*)&B_s[k * 132 + c4] = *(const float4*)(W + (size_t)(kk + k) * 128 + c4);
            }
            __syncthreads();
#pragma unroll 8
            for (int k = 0; k < 32; ++k) {
                float av[8], bv[4];
                *(float4*)&av[0] = *(const float4*)&A_s[k * 132 + tr * 8];
                *(float4*)&av[4] = *(const float4*)&A_s[k * 132 + tr * 8 + 4];
                *(float4*)&bv[0] = *(const float4*)&B_s[k * 132 + tc * 4];
#pragma unroll
                for (int i = 0; i < 8; ++i)
#pragma unroll
                    for (int j = 0; j < 4; ++j) acc[i][j] = fmaf(av[i], bv[j], acc[i][j]);
            }
        }
#pragma unroll
        for (int i = 0; i < 8; ++i) {
            int node = tr * 8 + i;
            if (node < 125) {
                float4 o = {acc[i][0], acc[i][1], acc[i][2], acc[i][3]};
                *(float4*)(Ob + ((size_t)(b * 1000) + n0 + node) * 128 + tc * 4) = o;
            }
        }
    } else if (blk < 1024) {
        // ---- top-21 + xs rows: 8 bp per block, one wave each, register-only ----
        int w = tid >> 6, lane = tid & 63;
        int bp = (blk - 512) * 8 + w;
        const float* drow = dist + (size_t)bp * 1000;
        unsigned long long key[16];
#pragma unroll
        for (int j = 0; j < 16; ++j) {
            int n = j * 64 + lane;
            key[j] = (n < 1000)
                ? ((((unsigned long long)__float_as_uint(drow[n])) << 32) | (unsigned)n)
                : ~0ull;
        }
        float myv = 0.f, v10 = 0.f, v20 = 0.f;
        int myi = 0;
        for (int t = 0; t < 21; ++t) {
            unsigned long long kmin = key[0];
            int jm = 0;
#pragma unroll
            for (int j = 1; j < 16; ++j)
                if (key[j] < kmin) { kmin = key[j]; jm = j; }
            unsigned long long g = kmin;
#pragma unroll
            for (int o = 1; o < 64; o <<= 1) {
                unsigned long long o2 = __shfl_xor(g, o, 64);
                g = (o2 < g) ? o2 : g;
            }
            if (kmin == g) key[jm] = ~0ull;
            float gv = __uint_as_float((unsigned)(g >> 32));
            if (t == lane) { myv = gv; myi = (int)(g & 0xffffffffu); }
            if (t == 10) v10 = gv;
            if (t == 20) v20 = gv;
        }
        if (lane < 21) {
            float th = theta[(size_t)bp * 1000 + myi];
            IDX[(size_t)bp * 21 + lane] = myi;
            float sd1 = myv / v20;
            XS1[(size_t)bp * 44 + lane] = sd1;
            XS1[(size_t)bp * 44 + 21 + lane] = th;
            SD1[(size_t)bp * 21 + lane] = sd1;
            if (lane < 11) {
                float sd0 = myv / v10;
                XS0[(size_t)bp * 24 + lane] = sd0;
                XS0[(size_t)bp * 24 + 11 + lane] = th;
                SD0[(size_t)bp * 11 + lane] = sd0;
            }
        }
        if (lane == 0) {
            float a = f0[bp], c = f1[bp];
            XS0[(size_t)bp * 24 + 22] = a;
            XS0[(size_t)bp * 24 + 23] = c;
            XS1[(size_t)bp * 44 + 42] = a;
            XS1[(size_t)bp * 44 + 43] = c;
        }
    } else if (blk < 1088) {
        // ---- Q projection as GEMM: 64 rows x 128 cols, K=128 in 32-k chunks + load col ----
        int r0 = (blk - 1024) * 64;
        float* A_s = smem;          // [32][68]
        float* B_s = smem + 2176;   // [32][132]
        int tr = tid >> 5, tc = tid & 31;
        float acc[4][4];
#pragma unroll
        for (int i = 0; i < 4; i++)
#pragma unroll
            for (int j = 0; j < 4; j++) acc[i][j] = 0.f;
        for (int kk = 0; kk < 128; kk += 32) {
            if (kk) __syncthreads();
            for (int f = tid; f < 512; f += 512) {
                int row = f >> 3, k4 = (f & 7) * 4;
                float4 v = *(const float4*)(eln + (size_t)(r0 + row) * 128 + kk + k4);
                A_s[(k4 + 0) * 68 + row] = v.x;
                A_s[(k4 + 1) * 68 + row] = v.y;
                A_s[(k4 + 2) * 68 + row] = v.z;
                A_s[(k4 + 3) * 68 + row] = v.w;
            }
            for (int f = tid; f < 1024; f += 512) {
                int k = f >> 5, c4 = (f & 31) * 4;
                *(float4*)&B_s[k * 132 + c4] = *(const float4*)(Wq + (size_t)(kk + k) * 128 + c4);
            }
            __syncthreads();
#pragma unroll 8
            for (int k = 0; k < 32; ++k) {
                float av[4], bv[4];
                *(float4*)&av[0] = *(const float4*)&A_s[k * 68 + tr * 4];
                *(float4*)&bv[0] = *(const float4*)&B_s[k * 132 + tc * 4];
#pragma unroll
                for (int i = 0; i < 4; ++i)
#pragma unroll
                    for (int j = 0; j < 4; ++j) acc[i][j] = fmaf(av[i], bv[j], acc[i][j]);
            }
        }
#pragma unroll
        for (int i = 0; i < 4; ++i) {
            int row = r0 + tr * 4 + i;
            float lv = load[row];
#pragma unroll
            for (int j = 0; j < 4; ++j) {
                float wv = Wq[16384 + tc * 4 + j];
                acc[i][j] = fmaf(lv, wv, acc[i][j]) * 0.25f;
            }
            float4 o = {acc[i][0], acc[i][1], acc[i][2], acc[i][3]};
            *(float4*)(Q + (size_t)row * 128 + tc * 4) = o;
        }
    } else {
        // ---- mask transpose: two 32x32 tiles per block ----
        int t2 = (blk - 1088) * 2 + (tid >> 8);
        int tl = tid & 255;
        int b = t2 >> 7, pt = (t2 >> 5) & 3, nt = t2 & 31;
        int tx = tl & 31, ty = tl >> 5;
        float* t = smem + (tid >> 8) * 1056;  // [32][33]
        int p0 = pt * 32, n0 = nt * 32;
#pragma unroll
        for (int r = 0; r < 32; r += 8) {
            int pp = p0 + ty + r, nn = n0 + tx;
            t[(ty + r) * 33 + tx] = (nn < 1000) ? mask[((size_t)b * 128 + pp) * 1000 + nn] : 0.f;
        }
        __syncthreads();
#pragma unroll
        for (int r = 0; r < 32; r += 8) {
            int nn = n0 + ty + r, pp = p0 + tx;
            if (nn < 1000) maskT[((size_t)b * 1000 + nn) * 128 + pp] = t[tx * 33 + ty + r];
        }
    }
}

// ================== ATTENTION: standalone, full-n, K+V in LDS, 1-deep prefetch ==================
__global__ __launch_bounds__(512) void attn5(const float* __restrict__ Q,
                                             const float* __restrict__ Kb,
                                             const float* __restrict__ Vb,
                                             const float* __restrict__ maskT,
                                             float* __restrict__ OC) {
    int blk = blockIdx.x;
    int b = blk & 31, h = blk >> 5;
    int tid = threadIdx.x;
    __shared__ float lds[32000];
    float4* K4 = (float4*)lds;
    float4* V4 = (float4*)(lds + 16000);
    const size_t baseKV = (size_t)b * 128000 + h * 16;
    for (int f = tid; f < 4000; f += 512) {
        int n = f >> 2, d4 = f & 3;
        K4[f] = *(const float4*)(Kb + baseKV + (size_t)n * 128 + d4 * 4);
        V4[f] = *(const float4*)(Vb + baseKV + (size_t)n * 128 + d4 * 4);
    }
    int pg = tid & 31, ng = tid >> 5;
    int p0 = pg * 4;
    float4 qr[4][4];
#pragma unroll
    for (int j = 0; j < 4; ++j) {
        const float* qp = Q + ((size_t)(b * 128 + p0 + j)) * 128 + h * 16;
#pragma unroll
        for (int d4 = 0; d4 < 4; ++d4) qr[j][d4] = *(const float4*)(qp + d4 * 4);
    }
    const float* mT = maskT + (size_t)b * 128000 + p0;
    __syncthreads();

    float4 z = {0.f, 0.f, 0.f, 0.f};
    float4 Oa[4][4];
    float l4[4] = {0.f, 0.f, 0.f, 0.f};
#pragma unroll
    for (int j = 0; j < 4; ++j)
#pragma unroll
        for (int d4 = 0; d4 < 4; ++d4) Oa[j][d4] = z;

    int nlim = (ng < 8) ? 63 : 62;
    int n = ng;
    float4 k0 = K4[n * 4], k1 = K4[n * 4 + 1], k2 = K4[n * 4 + 2], k3 = K4[n * 4 + 3];
    float4 v0 = V4[n * 4], v1 = V4[n * 4 + 1], v2 = V4[n * 4 + 2], v3 = V4[n * 4 + 3];
    float4 mv = *(const float4*)(mT + (size_t)n * 128);
#pragma unroll 1
    for (int i = 0; i < nlim; ++i) {
        int nn = n + 16;
        nn = (nn < 1000) ? nn : n;
        int nn4 = nn * 4;
        float4 K0 = K4[nn4], K1 = K4[nn4 + 1], K2 = K4[nn4 + 2], K3 = K4[nn4 + 3];
        float4 V0 = V4[nn4], V1 = V4[nn4 + 1], V2 = V4[nn4 + 2], V3 = V4[nn4 + 3];
        float4 MV = *(const float4*)(mT + (size_t)nn * 128);
        float mva[4] = {mv.x, mv.y, mv.z, mv.w};
#pragma unroll
        for (int j = 0; j < 4; ++j) {
            float sA = qr[j][0].x * k0.x;
            sA = fmaf(qr[j][0].y, k0.y, sA);
            sA = fmaf(qr[j][0].z, k0.z, sA);
            sA = fmaf(qr[j][0].w, k0.w, sA);
            sA = fmaf(qr[j][1].x, k1.x, sA);
            sA = fmaf(qr[j][1].y, k1.y, sA);
            sA = fmaf(qr[j][1].z, k1.z, sA);
            sA = fmaf(qr[j][1].w, k1.w, sA);
            float sB = fmaf(qr[j][2].x, k2.x, mva[j]);
            sB = fmaf(qr[j][2].y, k2.y, sB);
            sB = fmaf(qr[j][2].z, k2.z, sB);
            sB = fmaf(qr[j][2].w, k2.w, sB);
            sB = fmaf(qr[j][3].x, k3.x, sB);
            sB = fmaf(qr[j][3].y, k3.y, sB);
            sB = fmaf(qr[j][3].z, k3.z, sB);
            sB = fmaf(qr[j][3].w, k3.w, sB);
            float e = __expf(sA + sB);
            l4[j] += e;
            Oa[j][0].x = fmaf(e, v0.x, Oa[j][0].x);
            Oa[j][0].y = fmaf(e, v0.y, Oa[j][0].y);
            Oa[j][0].z = fmaf(e, v0.z, Oa[j][0].z);
            Oa[j][0].w = fmaf(e, v0.w, Oa[j][0].w);
            Oa[j][1].x = fmaf(e, v1.x, Oa[j][1].x);
            Oa[j][1].y = fmaf(e, v1.y, Oa[j][1].y);
            Oa[j][1].z = fmaf(e, v1.z, Oa[j][1].z);
            Oa[j][1].w = fmaf(e, v1.w, Oa[j][1].w);
            Oa[j][2].x = fmaf(e, v2.x, Oa[j][2].x);
            Oa[j][2].y = fmaf(e, v2.y, Oa[j][2].y);
            Oa[j][2].z = fmaf(e, v2.z, Oa[j][2].z);
            Oa[j][2].w = fmaf(e, v2.w, Oa[j][2].w);
            Oa[j][3].x = fmaf(e, v3.x, Oa[j][3].x);
            Oa[j][3].y = fmaf(e, v3.y, Oa[j][3].y);
            Oa[j][3].z = fmaf(e, v3.z, Oa[j][3].z);
            Oa[j][3].w = fmaf(e, v3.w, Oa[j][3].w);
        }
        k0 = K0; k1 = K1; k2 = K2; k3 = K3;
        v0 = V0; v1 = V1; v2 = V2; v3 = V3;
        mv = MV;
        n = nn;
    }
#pragma unroll
    for (int j = 0; j < 4; ++j) {
        l4[j] += __shfl_xor(l4[j], 32, 64);
#pragma unroll
        for (int d4 = 0; d4 < 4; ++d4) {
            Oa[j][d4].x += __shfl_xor(Oa[j][d4].x, 32, 64);
            Oa[j][d4].y += __shfl_xor(Oa[j][d4].y, 32, 64);
            Oa[j][d4].z += __shfl_xor(Oa[j][d4].z, 32, 64);
            Oa[j][d4].w += __shfl_xor(Oa[j][d4].w, 32, 64);
        }
    }
    __syncthreads();
    float* part = lds;  // [8 w][128 p][20]
    if ((tid & 32) == 0) {
        int w = tid >> 6;
#pragma unroll
        for (int j = 0; j < 4; ++j) {
            float* pr = part + w * 2560 + (p0 + j) * 20;
#pragma unroll
            for (int d4 = 0; d4 < 4; ++d4) *(float4*)(pr + d4 * 4) = Oa[j][d4];
            pr[16] = l4[j];
        }
    }
    __syncthreads();
    {
        int p = tid >> 2, dg = tid & 3;
        float lsum = 0.f;
        float4 o = z;
#pragma unroll
        for (int w = 0; w < 8; ++w) {
            const float* pr = part + w * 2560 + p * 20;
            lsum += pr[16];
            float4 t = *(const float4*)(pr + dg * 4);
            o.x += t.x; o.y += t.y; o.z += t.z; o.w += t.w;
        }
        float inv = 1.f / lsum;
        float4 r = {o.x * inv, o.y * inv, o.z * inv, o.w * inv};
        *(float4*)(OC + ((size_t)(b * 128 + p)) * 128 + h * 16 + dg * 4) = r;
    }
}

// ================== POLICY FRONT: standalone ==================
__global__ __launch_bounds__(512) void pfront(
    const float* __restrict__ XS0, const float* __restrict__ XS1,
    const float* __restrict__ w1_0, const float* __restrict__ b1_0,
    const float* __restrict__ w2_0, const float* __restrict__ b2_0,
    const float* __restrict__ w1_1, const float* __restrict__ b1_1,
    const float* __restrict__ w2_1, const float* __restrict__ b2_1,
    float* __restrict__ Hb0, float* __restrict__ Hb1) {
    __shared__ float smem[12320];
    int fb = blockIdx.x;
    int tid = threadIdx.x;
    int pol = fb & 1, colT = (fb >> 1) & 1, rowT = fb >> 2;
    int r0 = rowT * 64, c0 = colT * 128;
    const float* XS = pol ? XS1 : XS0;
    const float* w1 = pol ? w1_1 : w1_0;
    const float* b1 = pol ? b1_1 : b1_0;
    const float* w2 = pol ? w2_1 : w2_0;
    const float* b2 = pol ? b2_1 : b2_0;
    float* Hb = pol ? Hb1 : Hb0;
    int XSW = pol ? 44 : 24;
    float* xs_s = smem;          // [64][44]
    float* e_s = smem + 2816;    // [64][132]
    float* B_s = smem + 11264;   // [8][132]
    for (int f = tid; f < 64 * XSW; f += 512) {
        int r = f / XSW, k = f % XSW;
        xs_s[r * 44 + k] = XS[(size_t)(r0 + r) * XSW + k];
    }
    __syncthreads();
#pragma unroll
    for (int i = 0; i < 16; ++i) {
        int f = tid + i * 512;
        int r = f >> 7, c = f & 127;
        float acc = b1[c];
        for (int k = 0; k < XSW; ++k) acc = fmaf(xs_s[r * 44 + k], w1[k * 128 + c], acc);
        e_s[r * 132 + c] = fmaxf(acc, 0.f);
    }
    __syncthreads();
    int tr = tid >> 5, tc = tid & 31;
    float acc[4][4];
#pragma unroll
    for (int jj = 0; jj < 4; ++jj) {
        float bb = b2[c0 + tc * 4 + jj];
#pragma unroll
        for (int j = 0; j < 4; ++j) acc[j][jj] = bb;
    }
    for (int kk = 0; kk < 128; kk += 8) {
#pragma unroll
        for (int f = tid; f < 1024; f += 512) {
            int k = f >> 7, c = f & 127;
            B_s[k * 132 + c] = w2[(size_t)(kk + k) * 256 + c0 + c];
        }
        __syncthreads();
#pragma unroll
        for (int k = 0; k < 8; ++k) {
            float av[4], bv[4];
#pragma unroll
            for (int j = 0; j < 4; ++j) av[j] = e_s[(tr * 4 + j) * 132 + kk + k];
            *(float4*)&bv[0] = *(const float4*)&B_s[k * 132 + tc * 4];
#pragma unroll
            for (int j = 0; j < 4; ++j)
#pragma unroll
                for (int jj = 0; jj < 4; ++jj) acc[j][jj] = fmaf(av[j], bv[jj], acc[j][jj]);
        }
        __syncthreads();
    }
#pragma unroll
    for (int j = 0; j < 4; ++j) {
        float4 o = {fmaxf(acc[j][0], 0.f), fmaxf(acc[j][1], 0.f),
                    fmaxf(acc[j][2], 0.f), fmaxf(acc[j][3], 0.f)};
        *(float4*)(Hb + (size_t)(r0 + tr * 4 + j) * 256 + c0 + tc * 4) = o;
    }
}

// ================== MEGA 3: comb_proj | inorm ==================
__global__ __launch_bounds__(512) void mega3(
    const float* __restrict__ OC, const float* __restrict__ Wc, const float* __restrict__ bc,
    float* __restrict__ MH,
    const float* __restrict__ Hb0, const float* __restrict__ Hb1,
    float* __restrict__ MUb, float* __restrict__ RSb) {
    __shared__ float smem[1056];
    int blk = blockIdx.x;
    int tid = threadIdx.x;
    if (blk < 512) {
        int r0 = blk * 8;
        float* x_s = smem;  // [8][129]
#pragma unroll
        for (int f = tid; f < 1024; f += 512) {
            int r = f >> 7, c = f & 127;
            x_s[r * 129 + c] = OC[(size_t)(r0 + r) * 128 + c];
        }
        __syncthreads();
        int rr = tid >> 7, c = tid & 127;
        float a0 = bc[c], a1 = a0;
#pragma unroll 4
        for (int k = 0; k < 128; ++k) {
            float wv = Wc[k * 128 + c];
            a0 = fmaf(x_s[rr * 129 + k], wv, a0);
            a1 = fmaf(x_s[(rr + 4) * 129 + k], wv, a1);
        }
        MH[(size_t)(r0 + rr) * 128 + c] = a0;
        MH[(size_t)(r0 + rr + 4) * 128 + c] = a1;
    } else {
        int ib = blk - 512;
        int pol = ib & 1, b = ib >> 1;
        const float* Hb = pol ? Hb1 : Hb0;
        int c = tid & 255, half = tid >> 8;
        float s = 0.f, s2 = 0.f;
        int pbase = half * 64;
        for (int p = pbase; p < pbase + 64; ++p) {
            float v = Hb[((size_t)(b * 128 + p)) * 256 + c];
            s += v;
            s2 += v * v;
        }
        float* s_s = smem;
        float* s2_s = smem + 512;
        s_s[half * 256 + c] = s;
        s2_s[half * 256 + c] = s2;
        __syncthreads();
        if (half == 0) {
            float S = s_s[c] + s_s[256 + c];
            float S2 = s2_s[c] + s2_s[256 + c];
            float mu = S * (1.f / 128.f);
            float var = S2 * (1.f / 128.f) - mu * mu;
            MUb[pol * 8192 + b * 256 + c] = mu;
            RSb[pol * 8192 + b * 256 + c] = rsqrtf(var + EPS);
        }
    }
}

// ================== MEGA 4: policy_back (32-row tiles) | gemm_score ==================
// grid = 768 x 512 thr. [0,256) back, [256,768) score
__global__ __launch_bounds__(512) void mega4(
    const float* __restrict__ MH, const float* __restrict__ enc, float* __restrict__ SC,
    const float* __restrict__ Hb0, const float* __restrict__ Hb1,
    const float* __restrict__ MUb, const float* __restrict__ RSb,
    const float* __restrict__ g0, const float* __restrict__ be0,
    const float* __restrict__ w3_0, const float* __restrict__ b3_0,
    const float* __restrict__ w4_0, const float* __restrict__ b4_0,
    const float* __restrict__ g1, const float* __restrict__ be1,
    const float* __restrict__ w3_1, const float* __restrict__ b3_1,
    const float* __restrict__ w4_1, const float* __restrict__ b4_1,
    const float* __restrict__ SD0, const float* __restrict__ SD1,
    float* __restrict__ OUT0, float* __restrict__ OUT1) {
    __shared__ float smem[10112];
    int blk = blockIdx.x;
    int tid = threadIdx.x;
    if (blk < 256) {
        // ---- policy back: 32 rows x 128 cols, K=256 in 32-k chunks ----
        int pol = blk & 1, rowT = blk >> 1;
        int r0 = rowT * 32, b = r0 >> 7;
        const float* Hb = pol ? Hb1 : Hb0;
        const float* MU = MUb + pol * 8192 + b * 256;
        const float* RS = RSb + pol * 8192 + b * 256;
        const float* gg = pol ? g1 : g0;
        const float* bbv = pol ? be1 : be0;
        const float* w3 = pol ? w3_1 : w3_0;
        const float* pb3 = pol ? b3_1 : b3_0;
        const float* w4 = pol ? w4_1 : w4_0;
        const float* pb4 = pol ? b4_1 : b4_0;
        const float* SD = pol ? SD1 : SD0;
        float* OUT = pol ? OUT1 : OUT0;
        int ls = pol ? 21 : 11;
        float* scale_s = smem;            // [256]
        float* shift_s = smem + 256;      // [256]
        float* A_s = smem + 512;          // [32][36]
        float* B_s = smem + 1664;         // [32][132]
        float* e2_s = smem + 5888;        // [32][132]
        if (tid < 256) {
            float sc = RS[tid] * gg[tid];
            scale_s[tid] = sc;
            shift_s[tid] = bbv[tid] - MU[tid] * sc;
        }
        __syncthreads();
        int tr = tid >> 5, tc = tid & 31;
        float acc[2][4];
#pragma unroll
        for (int jj = 0; jj < 4; ++jj) {
            float bv = pb3[tc * 4 + jj];
            acc[0][jj] = bv;
            acc[1][jj] = bv;
        }
        for (int kk = 0; kk < 256; kk += 32) {
            if (kk) __syncthreads();
#pragma unroll
            for (int f = tid; f < 1024; f += 512) {
                int r = f >> 5, k = f & 31;
                float v = Hb[(size_t)(r0 + r) * 256 + kk + k];
                A_s[k * 36 + r] = v * scale_s[kk + k] + shift_s[kk + k];
            }
#pragma unroll
            for (int f = tid; f < 1024; f += 512) {
                int k = f >> 5, c4 = (f & 31) * 4;
                *(float4*)&B_s[k * 132 + c4] =
                    *(const float4*)(w3 + (size_t)(kk + k) * 128 + c4);
            }
            __syncthreads();
#pragma unroll 8
            for (int k = 0; k < 32; ++k) {
                float a0 = A_s[k * 36 + tr * 2];
                float a1 = A_s[k * 36 + tr * 2 + 1];
                float bv[4];
                *(float4*)&bv[0] = *(const float4*)&B_s[k * 132 + tc * 4];
#pragma unroll
                for (int jj = 0; jj < 4; ++jj) {
                    acc[0][jj] = fmaf(a0, bv[jj], acc[0][jj]);
                    acc[1][jj] = fmaf(a1, bv[jj], acc[1][jj]);
                }
            }
        }
        __syncthreads();
#pragma unroll
        for (int j = 0; j < 2; ++j) {
            float4 o = {fmaxf(acc[j][0], 0.f), fmaxf(acc[j][1], 0.f),
                        fmaxf(acc[j][2], 0.f), fmaxf(acc[j][3], 0.f)};
            *(float4*)&e2_s[(tr * 2 + j) * 132 + tc * 4] = o;
        }
        __syncthreads();
        for (int o = tid; o < 32 * ls; o += 512) {
            int row = o / ls, c = o % ls;
            float a = pb4[c];
#pragma unroll 4
            for (int k = 0; k < 128; ++k) a = fmaf(e2_s[row * 132 + k], w4[k * ls + c], a);
            OUT[(size_t)(r0 + row) * ls + c] = a - SD[(size_t)(r0 + row) * ls + c];
        }
    } else {
        // ---- node scores: 64 p x 125 n tile, K=128 in 32-k chunks, 4x4/thread ----
        int sb = blk - 256;
        int ph = sb & 1, chunk = (sb >> 1) & 7, b = sb >> 4;
        int n0 = chunk * 125, p0 = ph * 64;
        float* A_s = smem;          // [32][68]
        float* B_s = smem + 2176;   // [32][132]
        int tr = tid >> 5, tc = tid & 31;
        float acc[4][4];
#pragma unroll
        for (int i = 0; i < 4; i++)
#pragma unroll
            for (int j = 0; j < 4; j++) acc[i][j] = 0.f;
        for (int kk = 0; kk < 128; kk += 32) {
            if (kk) __syncthreads();
            for (int f = tid; f < 512; f += 512) {
                int row = f >> 3, k4 = (f & 7) * 4;
                float4 v = *(const float4*)(MH + ((size_t)(b * 128) + p0 + row) * 128 + kk + k4);
                A_s[(k4 + 0) * 68 + row] = v.x;
                A_s[(k4 + 1) * 68 + row] = v.y;
                A_s[(k4 + 2) * 68 + row] = v.z;
                A_s[(k4 + 3) * 68 + row] = v.w;
            }
            for (int f = tid; f < 1000; f += 512) {
                int nn = f >> 3, k4 = (f & 7) * 4;
                float4 v = *(const float4*)(enc + ((size_t)(b * 1000) + n0 + nn) * 128 + kk + k4);
                B_s[(k4 + 0) * 132 + nn] = v.x;
                B_s[(k4 + 1) * 132 + nn] = v.y;
                B_s[(k4 + 2) * 132 + nn] = v.z;
                B_s[(k4 + 3) * 132 + nn] = v.w;
            }
            __syncthreads();
#pragma unroll 8
            for (int k = 0; k < 32; ++k) {
                float av[4], bv[4];
                *(float4*)&av[0] = *(const float4*)&A_s[k * 68 + tr * 4];
                *(float4*)&bv[0] = *(const float4*)&B_s[k * 132 + tc * 4];
#pragma unroll
                for (int i = 0; i < 4; ++i)
#pragma unroll
                    for (int j = 0; j < 4; ++j) acc[i][j] = fmaf(av[i], bv[j], acc[i][j]);
            }
        }
        const float invs = 0.08838834764831845f;
#pragma unroll
        for (int i = 0; i < 4; ++i) {
            int pp = p0 + tr * 4 + i;
#pragma unroll
            for (int j = 0; j < 4; ++j) {
                int n = tc * 4 + j;
                if (n < 125) SC[((size_t)(b * 128) + pp) * 1000 + n0 + n] = acc[i][j] * invs;
            }
        }
    }
}

// ---------------- final softmax ----------------
__device__ inline float blockReduceMaxF(float v, volatile float* red) {
#pragma unroll
    for (int o = 32; o > 0; o >>= 1) v = fmaxf(v, __shfl_xor(v, o, 64));
    if ((threadIdx.x & 63) == 0) red[threadIdx.x >> 6] = v;
    __syncthreads();
    float r = fmaxf(fmaxf(red[0], red[1]), fmaxf(red[2], red[3]));
    __syncthreads();
    return r;
}

__device__ inline float blockReduceSumF(float v, volatile float* red) {
#pragma unroll
    for (int o = 32; o > 0; o >>= 1) v += __shfl_xor(v, o, 64);
    if ((threadIdx.x & 63) == 0) red[threadIdx.x >> 6] = v;
    __syncthreads();
    float r = red[0] + red[1] + red[2] + red[3];
    __syncthreads();
    return r;
}

__global__ void final_softmax(const float* SC, const float* __restrict__ mask,
                              const int* __restrict__ IDX, const float* __restrict__ OUT0,
                              const float* __restrict__ OUT1, float* out) {
    int bp = blockIdx.x;
    int tid = threadIdx.x;
    __shared__ float a0[1000];
    __shared__ float a1[1000];
    __shared__ float red[4];
    for (int n = tid; n < 1000; n += 256) {
        a0[n] = PEN;
        a1[n] = PEN;
    }
    __syncthreads();
    if (tid < 11) a0[IDX[bp * 21 + tid]] = OUT0[bp * 11 + tid];
    if (tid < 21) a1[IDX[bp * 21 + tid]] = OUT1[bp * 21 + tid];
    __syncthreads();
    float logit[4];
    float lmax = -INFINITY;
    {
        int i = 0;
        for (int n = tid; n < 1000; n += 256, i++) {
            float sc = SC[(size_t)bp * 1000 + n] + 0.5f * (a0[n] + a1[n]);
            float zz = __expf(2.f * sc);
            float t = 1.f - 2.f / (zz + 1.f);
            float lg = CLIP * t + mask[(size_t)bp * 1000 + n];
            logit[i] = lg;
            lmax = fmaxf(lmax, lg);
        }
    }
    float m = blockReduceMaxF(lmax, red);
    float lsum = 0.f;
    {
        int i = 0;
        for (int n = tid; n < 1000; n += 256, i++) {
            float e = __expf(logit[i] - m);
            logit[i] = e;
            lsum += e;
        }
    }
    float s = blockReduceSumF(lsum, red);
    float inv = 1.f / s;
    {
        int i = 0;
        for (int n = tid; n < 1000; n += 256, i++) out[(size_t)bp * 1000 + n] = logit[i] * inv;
    }
}

// ---------------- launcher ----------------
extern "C" void kernel_launch(void* const* d_in, const int* in_sizes, int n_in,
                              void* d_out, int out_size, void* d_ws, size_t ws_size,
                              hipStream_t stream) {
    const float* eln   = (const float*)d_in[0];
    const float* load  = (const float*)d_in[1];
    const float* dist  = (const float*)d_in[2];
    const float* theta = (const float*)d_in[3];
    const float* f0    = (const float*)d_in[4];
    const float* f1    = (const float*)d_in[5];
    const float* mask  = (const float*)d_in[6];
    const float* enc   = (const float*)d_in[7];
    const float* Wq    = (const float*)d_in[8];
    const float* Wk    = (const float*)d_in[9];
    const float* Wv    = (const float*)d_in[10];
    const float* Wc    = (const float*)d_in[11];
    const float* bc    = (const float*)d_in[12];
    const float* p0w1 = (const float*)d_in[13];
    const float* p0b1 = (const float*)d_in[14];
    const float* p0w2 = (const float*)d_in[15];
    const float* p0b2 = (const float*)d_in[16];
    const float* p0w3 = (const float*)d_in[17];
    const float* p0b3 = (const float*)d_in[18];
    const float* p0w4 = (const float*)d_in[19];
    const float* p0b4 = (const float*)d_in[20];
    const float* p0g  = (const float*)d_in[21];
    const float* p0be = (const float*)d_in[22];
    const float* p1w1 = (const float*)d_in[23];
    const float* p1b1 = (const float*)d_in[24];
    const float* p1w2 = (const float*)d_in[25];
    const float* p1b2 = (const float*)d_in[26];
    const float* p1w3 = (const float*)d_in[27];
    const float* p1b3 = (const float*)d_in[28];
    const float* p1w4 = (const float*)d_in[29];
    const float* p1b4 = (const float*)d_in[30];
    const float* p1g  = (const float*)d_in[31];
    const float* p1be = (const float*)d_in[32];

    float* out = (float*)d_out;

    float* ws = (float*)d_ws;
    float* Kb   = ws;                     // 4,096,000
    float* Vb   = Kb + 4096000;           // 4,096,000
    float* Qb   = Vb + 4096000;           // 524,288
    float* OCb  = Qb + 524288;            // 524,288
    float* MHb  = OCb + 524288;           // 524,288
    float* Hb0  = MHb + 524288;           // 1,048,576
    float* Hb1  = Hb0 + 1048576;          // 1,048,576
    float* MUb  = Hb1 + 1048576;          // 16,384
    float* RSb  = MUb + 16384;            // 16,384
    float* SD0  = RSb + 16384;            // 45,056
    float* SD1  = SD0 + 45056;            // 86,016
    float* OUT0 = SD1 + 86016;            // 45,056
    float* OUT1 = OUT0 + 45056;           // 86,016
    int*   IDX  = (int*)(OUT1 + 86016);   // 86,016 ints
    float* XS0  = (float*)(IDX + 86016);  // 98,304
    float* XS1  = XS0 + 98304;            // 180,224

    float* maskT = out;
    float* SC = out;

    mega1<<<3136, 512, 0, stream>>>(enc, Wk, Wv, Kb, Vb,
                                    eln, load, Wq, Qb,
                                    mask, maskT,
                                    dist, theta, f0, f1, XS0, XS1, SD0, SD1, IDX);
    attn5<<<256, 512, 0, stream>>>(Qb, Kb, Vb, maskT, OCb);
    pfront<<<256, 512, 0, stream>>>(XS0, XS1,
                                    p0w1, p0b1, p0w2, p0b2,
                                    p1w1, p1b1, p1w2, p1b2,
                                    Hb0, Hb1);
    mega3<<<576, 512, 0, stream>>>(OCb, Wc, bc, MHb, Hb0, Hb1, MUb, RSb);
    mega4<<<768, 512, 0, stream>>>(MHb, enc, SC,
                                   Hb0, Hb1, MUb, RSb,
                                   p0g, p0be, p0w3, p0b3, p0w4, p0b4,
                                   p1g, p1be, p1w3, p1b3, p1w4, p1b4,
                                   SD0, SD1, OUT0, OUT1);
    final_softmax<<<BB * PP, 256, 0, stream>>>(SC, mask, IDX, OUT0, OUT1, out);
}